// Round 10
// baseline (264.054 us; speedup 1.0000x reference)
//
#include <hip/hip_runtime.h>
#include <hip/hip_bf16.h>
#include <stdint.h>

#define DEVFN static __device__ __forceinline__

typedef __attribute__((ext_vector_type(8))) short bf16x8;
typedef __attribute__((ext_vector_type(4))) short s16x4;
typedef __attribute__((ext_vector_type(4))) float f32x4;

static constexpr int TOK = 8192;       // B*N
static constexpr int DIM = 768;
static constexpr int HEADS = 8;
static constexpr int HD = 96;
static constexpr int EXPERTS = 24;
static constexpr int NQ = 2304;        // EXPERTS*HD
static constexpr int NQP = 2560;       // NQ + 192 (kv) + 64 (zero pad)
static constexpr float C2 = 0.14724484f;   // HD^-0.5 * log2(e)
static constexpr float THRRAW = 78.0f;     // defer-max threshold, raw-score units

// ---- workspace layout (bytes) ----
static constexpr size_t OFF_XB   = 0;          // x bf16 [8192][768]   (o aliases)
static constexpr size_t OFF_BT1  = 12582912;   // Bt1 bf16 [2560][768]
static constexpr size_t OFF_W2T  = 16515072;   // W2t bf16 [768][2304]
static constexpr size_t OFF_K    = 20054016;   // Kp packed bf16 [128 tiles][12][64][8]
static constexpr size_t OFF_VT   = 21626880;   // Vp packed bf16 [128 tiles][8][96][8]
static constexpr size_t OFF_GATE = 23199744;   // gates f32 [8192][8]
static constexpr size_t OFF_TOPI = 23461888;   // topi i32 [8192][8]
static constexpr size_t OFF_AUX  = 23724032;   // me[24], fe[24], z
static constexpr size_t OFF_ALLQ = 23724288;   // allq bf16 [8192][2560]
// gating partials [8][24][8192] f32 = 6.29 MB alias into ALLQ region (dead before gemm1)
static constexpr size_t OFF_PART = OFF_ALLQ;

DEVFN short f2bf(float f){
  __hip_bfloat16 h = __float2bfloat16(f);
  return __builtin_bit_cast(short, h);
}
DEVFN float bf2f(short u){
  return __bfloat162float(__builtin_bit_cast(__hip_bfloat16, u));
}

DEVFN void gload16(const void* g, void* l){
  auto gp = reinterpret_cast<__attribute__((address_space(1))) unsigned int*>(
      reinterpret_cast<uintptr_t>(g));
  auto lp = reinterpret_cast<__attribute__((address_space(3))) unsigned int*>(
      reinterpret_cast<uintptr_t>(l));
  __builtin_amdgcn_global_load_lds(gp, lp, 16, 0, 0);
}

// ---------------- fused prep: weight casts / transposes (x-cast moved to gating_partial) ----------------
__global__ __launch_bounds__(256) void prep_kernel(const float* __restrict__ W1,
                                                   const float* __restrict__ Wkv,
                                                   const float* __restrict__ W2,
                                                   short* __restrict__ Bt1,
                                                   short* __restrict__ W2t){
  int bid = blockIdx.x, tid = threadIdx.x;
  if (bid < 6912){                                    // W1 -> Bt1[n][k]
    int i = bid*256 + tid;                            // 24*768*96
    int e = i / (DIM*HD);
    int rem = i - e*(DIM*HD);
    int d = rem / HD, hh = rem - d*HD;
    Bt1[(size_t)(e*HD + hh)*DIM + d] = f2bf(W1[i]);
  } else if (bid < 7488){                             // Wkv -> Bt1 kv rows
    int i = (bid-6912)*256 + tid;                     // 768*192
    int d = i / 192, j = i - d*192;
    Bt1[(size_t)(NQ + j)*DIM + d] = f2bf(Wkv[i]);
  } else if (bid < 7680){                             // zero pad rows
    int i = (bid-7488)*256 + tid;                     // 64*768
    Bt1[(size_t)(NQ + 192)*DIM + i] = 0;
  } else {                                            // W2 -> W2t[c][e*96+h]
    int i = (bid-7680)*256 + tid;                     // 24*96*768
    int e = i / (HD*DIM);
    int rem = i - e*(HD*DIM);
    int hh = rem / DIM, c = rem - hh*DIM;
    W2t[(size_t)c*NQ + e*HD + hh] = f2bf(W2[i]);
  }
}

// ---------------- gating G1: logit partials, lane=token, W via scalar pipe ----------------
// 1024 one-wave blocks: (tg in [0,128)) x (kc in [0,8)). Block stages x[64 tok][96 d]
// into pad-101 LDS (2 lanes/bank on read = free), also emits the bf16 cast of x.
// Inner loop: xv from LDS (per-lane), 24 W values wave-UNIFORM -> s_load + v_fma(v,s,v):
// VALU-bound at 24 independent chains. Partials [kc][e][token] coalesced.
__global__ __launch_bounds__(64) void gating_partial(const float* __restrict__ x,
                                                     const float* __restrict__ Wg,
                                                     const int* __restrict__ task,
                                                     short* __restrict__ xb,
                                                     float* __restrict__ partial){
  __shared__ float xl[64*101];
  int lane = threadIdx.x;
  int tg = blockIdx.x >> 3, kc = blockIdx.x & 7;
  int tok0 = tg*64, kbase = kc*96;
  const float* Wt = Wg + (size_t)task[0]*(DIM*EXPERTS) + (size_t)kbase*EXPERTS;

  // stage x[64][96] (f32, coalesced float4) + write bf16 cast
#pragma unroll
  for (int i = 0; i < 24; ++i){
    int c = i*64 + lane;               // 1536 chunks of 4 floats
    int t = c / 24, cc = c - t*24;
    size_t gidx = (size_t)(tok0+t)*DIM + kbase + cc*4;
    float4 v = *reinterpret_cast<const float4*>(x + gidx);
    float* dst = &xl[t*101 + cc*4];
    dst[0] = v.x; dst[1] = v.y; dst[2] = v.z; dst[3] = v.w;
    s16x4 o4;
    o4[0] = f2bf(v.x); o4[1] = f2bf(v.y); o4[2] = f2bf(v.z); o4[3] = f2bf(v.w);
    *reinterpret_cast<s16x4*>(xb + gidx) = o4;
  }
  __syncthreads();

  float acc[EXPERTS];
#pragma unroll
  for (int e = 0; e < EXPERTS; ++e) acc[e] = 0.f;
  for (int d = 0; d < 96; ++d){
    float xv = xl[lane*101 + d];
    const float* wr = Wt + d*EXPERTS;  // wave-uniform address -> scalar loads
#pragma unroll
    for (int e = 0; e < EXPERTS; ++e) acc[e] = fmaf(xv, wr[e], acc[e]);
  }
#pragma unroll
  for (int e = 0; e < EXPERTS; ++e)
    partial[(size_t)(kc*EXPERTS + e)*TOK + tok0 + lane] = acc[e];
}

// ---------------- gating G2: combine partials (fixed order), top-8, gates, aux ----------------
__global__ __launch_bounds__(64) void gating_select(const float* __restrict__ partial,
                                                    int* __restrict__ topi,
                                                    float* __restrict__ gates,
                                                    float* __restrict__ auxbuf){
  __shared__ float lfr[EXPERTS];
  int lane = threadIdx.x;
  int token = blockIdx.x*64 + lane;
  if (lane < EXPERTS) lfr[lane] = 0.f;
  __syncthreads();

  float acc[EXPERTS];
#pragma unroll
  for (int e = 0; e < EXPERTS; ++e) acc[e] = 0.f;
#pragma unroll
  for (int kc = 0; kc < 8; ++kc)
#pragma unroll
    for (int e = 0; e < EXPERTS; ++e)
      acc[e] += partial[(size_t)(kc*EXPERTS + e)*TOK + token];  // ascending kc: deterministic

  // top-8 (strict >, lowest index wins ties -> matches lax.top_k on f32 logits)
  float mx = acc[0];
#pragma unroll
  for (int e = 1; e < EXPERTS; ++e) mx = fmaxf(mx, acc[e]);
  unsigned selm = 0; int sel[8]; float sg[8];
#pragma unroll
  for (int t = 0; t < 8; ++t){
    float best = -3.0e38f; int bi = 0;
#pragma unroll
    for (int e = 0; e < EXPERTS; ++e){
      bool ok = !((selm>>e)&1u) && (acc[e] > best);
      best = ok ? acc[e] : best;
      bi   = ok ? e      : bi;
    }
    selm |= (1u<<bi); sel[t] = bi; sg[t] = best;
  }

  float p[EXPERTS]; float S = 0.f;
#pragma unroll
  for (int e = 0; e < EXPERTS; ++e){ p[e] = __expf(acc[e] - mx); S += p[e]; }
  float lse = mx + __logf(S);
  float Sinv = 1.f/S;
  float gsum = 0.f; float pg[8];
#pragma unroll
  for (int t = 0; t < 8; ++t){ pg[t] = __expf(sg[t] - mx)*Sinv; gsum += pg[t]; }
  float dinv = 1.f/(gsum + 1e-6f);

#pragma unroll
  for (int t = 0; t < 8; ++t){
    topi[token*HEADS + t]  = sel[t];
    gates[token*HEADS + t] = pg[t]*dinv;
  }

  // aux: me via wave-reduce + 1 atomic/expert; fe via LDS; z via wave-reduce
  float z2 = lse*lse;
#pragma unroll
  for (int d = 1; d < 64; d <<= 1) z2 += __shfl_xor(z2, d, 64);
#pragma unroll
  for (int e = 0; e < EXPERTS; ++e){
    float v = p[e]*Sinv;
#pragma unroll
    for (int d = 1; d < 64; d <<= 1) v += __shfl_xor(v, d, 64);
    if (lane == 0) atomicAdd(&auxbuf[e], v);
  }
  if (lane == 0) atomicAdd(&auxbuf[2*EXPERTS], z2);
#pragma unroll
  for (int t = 0; t < 8; ++t) atomicAdd(&lfr[sel[t]], 1.f);
  __syncthreads();
  if (lane < EXPERTS) atomicAdd(&auxbuf[EXPERTS + lane], lfr[lane]);
}

__global__ void aux_final(const float* __restrict__ auxbuf, float* __restrict__ outa){
  if (threadIdx.x != 0 || blockIdx.x != 0) return;
  float ms = 0.f, fs = 0.f;
  for (int e=0;e<EXPERTS;++e){ ms += auxbuf[e]; fs += auxbuf[EXPERTS+e]; }
  float sw = 0.f;
  for (int e=0;e<EXPERTS;++e) sw += (auxbuf[e]/ms)*(auxbuf[EXPERTS+e]/fs);
  sw *= (float)EXPERTS;
  float z = auxbuf[2*EXPERTS] / (float)TOK;
  outa[0] = 0.1f*sw + 0.001f*z;
}

// ---------------- bf16 MFMA GEMM: 128x128 tile, XCD swizzle, T2 LDS swizzle ----------------
template<bool OUT_BF16>
__global__ __launch_bounds__(256) void gemm_bt(const short* __restrict__ A,
                                               const short* __restrict__ Bt,
                                               void* __restrict__ Cout,
                                               int M, int N, int K){
  __shared__ short As[128*64];
  __shared__ short Bs[128*64];
  int nwg = gridDim.x*gridDim.y;
  int orig = blockIdx.y*gridDim.x + blockIdx.x;
  int cpx = nwg >> 3;
  int swz = (orig & 7)*cpx + (orig >> 3);   // requires nwg % 8 == 0
  int bx = swz % gridDim.x, by = swz / gridDim.x;

  int tid = threadIdx.x;
  int lane = tid & 63, w = tid >> 6;
  int wr = w >> 1, wc = w & 1;
  int l15 = lane & 15, lg = lane >> 4;
  int m0 = by * 128, n0 = bx * 128;

  f32x4 acc[4][4] = {};

  for (int k0 = 0; k0 < K; k0 += 64){
#pragma unroll
    for (int it = 0; it < 4; ++it){
      int c = it*256 + tid;
      int row = c >> 3, cc = c & 7;
      int csrc = cc ^ (row & 7);            // pre-swizzled source chunk
      gload16(A  + (size_t)(m0+row)*K + k0 + csrc*8, (char*)As + (size_t)c*16);
      gload16(Bt + (size_t)(n0+row)*K + k0 + csrc*8, (char*)Bs + (size_t)c*16);
    }
    __syncthreads();
#pragma unroll
    for (int kk = 0; kk < 2; ++kk){
      bf16x8 af[4], bfr[4];
      int jp = (kk*4 + lg) ^ (l15 & 7);     // phys chunk for logical kk*4+lg
#pragma unroll
      for (int m = 0; m < 4; ++m)
        af[m] = *reinterpret_cast<const bf16x8*>(&As[(wr*64 + m*16 + l15)*64 + jp*8]);
#pragma unroll
      for (int n = 0; n < 4; ++n)
        bfr[n] = *reinterpret_cast<const bf16x8*>(&Bs[(wc*64 + n*16 + l15)*64 + jp*8]);
#pragma unroll
      for (int m = 0; m < 4; ++m)
#pragma unroll
        for (int n = 0; n < 4; ++n)
          acc[m][n] = __builtin_amdgcn_mfma_f32_16x16x32_bf16(af[m], bfr[n], acc[m][n], 0, 0, 0);
    }
    __syncthreads();
  }
#pragma unroll
  for (int m = 0; m < 4; ++m)
#pragma unroll
    for (int n = 0; n < 4; ++n){
      int rbase = m0 + wr*64 + m*16 + lg*4;
      int col   = n0 + wc*64 + n*16 + l15;
#pragma unroll
      for (int r = 0; r < 4; ++r){
        float v = acc[m][n][r];
        size_t idx = (size_t)(rbase + r)*N + col;
        if constexpr (OUT_BF16) ((short*)Cout)[idx] = f2bf(v);
        else                    ((float*)Cout)[idx] = v;
      }
    }
}

// ---------------- GEMM2 fused: dbuf LDS + T14 async gather pipeline ----------------
__global__ __launch_bounds__(256) void gemm2_fused(const short* __restrict__ o,
                                                   const int* __restrict__ topi,
                                                   const short* __restrict__ W2t,
                                                   float* __restrict__ out){
  __shared__ short As[2][128*64];
  __shared__ short Bs[2][64*64];
  __shared__ signed char hmap[128][24];
  int nwg = gridDim.x*gridDim.y;
  int orig = blockIdx.y*gridDim.x + blockIdx.x;
  int cpx = nwg >> 3;
  int swz = (orig & 7)*cpx + (orig >> 3);   // 12*64=768, %8==0
  int bx = swz % gridDim.x, by = swz / gridDim.x;

  int tid = threadIdx.x;
  int lane = tid & 63, w = tid >> 6;
  int l15 = lane & 15, lg = lane >> 4;
  int m0 = by * 128, n0 = bx * 64;

  int* hm32 = (int*)&hmap[0][0];
  for (int i = tid; i < 768; i += 256) hm32[i] = -1;   // all bytes 0xFF
  __syncthreads();
  for (int i = tid; i < 128*8; i += 256){
    int row = i >> 3, hh = i & 7;
    int e = topi[(size_t)(m0+row)*HEADS + hh];
    hmap[row][e] = (signed char)hh;
  }
  __syncthreads();

  // per-thread A-gather invariants: 4 chunks (row, cc)
  int arow[4], accv[4];
  size_t arbase[4];
#pragma unroll
  for (int it = 0; it < 4; ++it){
    int c = it*256 + tid;
    arow[it] = c >> 3; accv[it] = c & 7;
    arbase[it] = (size_t)(m0 + arow[it])*DIM;
  }

  f32x4 acc[2][4] = {};
  bf16x8 areg[4];

  // ---- staging helpers (inline) ----
#define STAGE_A(kt, dst)                                                     \
  {                                                                          \
    _Pragma("unroll")                                                        \
    for (int it = 0; it < 4; ++it){                                          \
      unsigned kc = (unsigned)((kt)*8 + accv[it]);                           \
      unsigned e = kc / 12u;                                                 \
      unsigned dc = kc - e*12u;                                              \
      int hh = hmap[arow[it]][e];                                            \
      bf16x8 av = {};                                                        \
      if (hh >= 0)                                                           \
        av = *reinterpret_cast<const bf16x8*>(o + arbase[it] + hh*HD + dc*8);\
      dst[it] = av;                                                          \
    }                                                                        \
  }
#define WRITE_A(buf, src)                                                    \
  {                                                                          \
    _Pragma("unroll")                                                        \
    for (int it = 0; it < 4; ++it)                                           \
      *reinterpret_cast<bf16x8*>(                                            \
        &As[buf][arow[it]*64 + ((accv[it] ^ (arow[it] & 7)))*8]) = src[it];  \
  }
#define STAGE_B(kt, buf)                                                     \
  {                                                                          \
    _Pragma("unroll")                                                        \
    for (int it = 0; it < 2; ++it){                                          \
      int c = it*256 + tid;                                                  \
      int row = c >> 3, cc = c & 7;                                          \
      int csrc = cc ^ (row & 7);                                             \
      gload16(W2t + (size_t)(n0+row)*NQ + (kt)*64 + csrc*8,                  \
              (char*)&Bs[buf][0] + (size_t)c*16);                            \
    }                                                                        \
  }

  // prologue
  STAGE_A(0, areg);
  STAGE_B(0, 0);
  WRITE_A(0, areg);
  __syncthreads();

  for (int kt = 0; kt < 36; ++kt){
    int buf = kt & 1;
    bf16x8 anext[4];
    if (kt < 35){
      STAGE_A(kt+1, anext);       // global loads in flight under MFMA
      STAGE_B(kt+1, buf^1);       // gload_lds in flight across barrier
    }
#pragma unroll
    for (int kk = 0; kk < 2; ++kk){
      int jp = (kk*4 + lg) ^ (l15 & 7);
      bf16x8 af[2], bfr[4];
#pragma unroll
      for (int m = 0; m < 2; ++m)
        af[m] = *reinterpret_cast<const bf16x8*>(&As[buf][(w*32 + m*16 + l15)*64 + jp*8]);
#pragma unroll
      for (int n = 0; n < 4; ++n)
        bfr[n] = *reinterpret_cast<const bf16x8*>(&Bs[buf][(n*16 + l15)*64 + jp*8]);
#pragma unroll
      for (int m = 0; m < 2; ++m)
#pragma unroll
        for (int n = 0; n < 4; ++n)
          acc[m][n] = __builtin_amdgcn_mfma_f32_16x16x32_bf16(af[m], bfr[n], acc[m][n], 0, 0, 0);
    }
    if (kt < 35) WRITE_A(buf^1, anext);
    __syncthreads();
  }
#undef STAGE_A
#undef WRITE_A
#undef STAGE_B

#pragma unroll
  for (int m = 0; m < 2; ++m)
#pragma unroll
    for (int n = 0; n < 4; ++n){
      int rbase = m0 + w*32 + m*16 + lg*4;
      int col   = n0 + n*16 + l15;
#pragma unroll
      for (int r = 0; r < 4; ++r)
        out[(size_t)(rbase + r)*DIM + col] = acc[m][n][r];
    }
}

// ---------------- split kv: bias + repack into fragment-chunk order ----------------
__global__ __launch_bounds__(256) void split_kv_tile(const short* __restrict__ allq,
                                                     const float* __restrict__ bkv,
                                                     short* __restrict__ Kp,
                                                     short* __restrict__ Vp){
  __shared__ short kv[64*192];
  int bt = blockIdx.x;                 // b*16 + nt
  int b = bt >> 4;
  int tid = threadIdx.x;
#pragma unroll
  for (int it = 0; it < 6; ++it){
    int c = it*256 + tid;              // 1536 chunks of 16B
    int j = c / 24, cc = c - j*24;
    int token = b*1024 + (bt & 15)*64 + j;
    gload16(allq + (size_t)token*NQP + NQ + cc*8, (char*)kv + (size_t)c*16);
  }
  __syncthreads();
#pragma unroll
  for (int it = 0; it < 3; ++it){
    int c = it*256 + tid;              // 768 K chunks
    int kc = c >> 6, j = c & 63;
    bf16x8 v = *reinterpret_cast<const bf16x8*>(&kv[j*192 + kc*8]);
    bf16x8 o8;
#pragma unroll
    for (int e = 0; e < 8; ++e) o8[e] = f2bf(bf2f(v[e]) + bkv[kc*8 + e]);
    *reinterpret_cast<bf16x8*>(Kp + ((size_t)bt*768 + c)*8) = o8;
  }
#pragma unroll
  for (int it = 0; it < 3; ++it){
    int c = it*256 + tid;              // 768 V chunks
    int kc = c / 96, hd = c - kc*96;
    float bias = bkv[96 + hd];
    bf16x8 o8;
#pragma unroll
    for (int e = 0; e < 8; ++e) o8[e] = f2bf(bf2f(kv[(kc*8 + e)*192 + 96 + hd]) + bias);
    *reinterpret_cast<bf16x8*>(Vp + ((size_t)bt*768 + c)*8) = o8;
  }
}

// ---------------- flash attention: 32 q-rows/wave, dbuf staging, lazy softmax, gate-folded ----------------
__global__ __launch_bounds__(256, 2) void attn_fwd(const short* __restrict__ allq,
                                                   const int* __restrict__ topi,
                                                   const float* __restrict__ gates,
                                                   const short* __restrict__ Kp,
                                                   const short* __restrict__ Vp,
                                                   short* __restrict__ o){
  __shared__ short Klds[2][768*8];
  __shared__ short Vlds[2][768*8];
  __shared__ short Plds[4][16*72];
  int qt = blockIdx.x, bh = blockIdx.y;        // qt in [0,8): 128 q-rows per block
  int b = bh >> 3, h = bh & 7;
  int tid = threadIdx.x;
  int lane = tid & 63, w = tid >> 6;
  int l15 = lane & 15, lg = lane >> 4;

  bf16x8 qf[2][3];
  int tok0 = b*1024 + qt*128 + w*32;
#pragma unroll
  for (int qm = 0; qm < 2; ++qm){
    int token = tok0 + qm*16 + l15;
    int qe = topi[token*HEADS + h];
    const short* qp = allq + (size_t)token*NQP + qe*HD;
#pragma unroll
    for (int t = 0; t < 3; ++t)
      qf[qm][t] = *reinterpret_cast<const bf16x8*>(qp + t*32 + lg*8);
  }

  f32x4 Oacc[2][6] = {};
  float mrun[2][4], lrun[2][4];
#pragma unroll
  for (int qm = 0; qm < 2; ++qm)
#pragma unroll
    for (int r = 0; r < 4; ++r){ mrun[qm][r] = -1.0e30f; lrun[qm][r] = 0.f; }

  const short* kb = Kp + (size_t)b*16*768*8;
  const short* vb = Vp + (size_t)b*16*768*8;

#pragma unroll
  for (int it = 0; it < 3; ++it){
    int c = it*256 + tid;
    gload16(kb + (size_t)c*8, (char*)&Klds[0][0] + (size_t)c*16);
    gload16(vb + (size_t)c*8, (char*)&Vlds[0][0] + (size_t)c*16);
  }
  __syncthreads();

  int cur = 0;
  for (int nt = 0; nt < 16; ++nt){
    if (nt < 15){
      const short* kn = kb + (size_t)(nt+1)*768*8;
      const short* vn = vb + (size_t)(nt+1)*768*8;
#pragma unroll
      for (int it = 0; it < 3; ++it){
        int c = it*256 + tid;
        gload16(kn + (size_t)c*8, (char*)&Klds[cur^1][0] + (size_t)c*16);
        gload16(vn + (size_t)c*8, (char*)&Vlds[cur^1][0] + (size_t)c*16);
      }
    }

    f32x4 sa[2][4];
    __builtin_amdgcn_s_setprio(1);
#pragma unroll
    for (int ct = 0; ct < 4; ++ct){
      bf16x8 kf[3];
#pragma unroll
      for (int t = 0; t < 3; ++t)
        kf[t] = *reinterpret_cast<const bf16x8*>(&Klds[cur][((t*4+lg)*64 + ct*16 + l15)*8]);
#pragma unroll
      for (int qm = 0; qm < 2; ++qm){
        f32x4 a = {};
#pragma unroll
        for (int t = 0; t < 3; ++t)
          a = __builtin_amdgcn_mfma_f32_16x16x32_bf16(qf[qm][t], kf[t], a, 0, 0, 0);
        sa[qm][ct] = a;
      }
    }
    __builtin_amdgcn_s_setprio(0);

    float pmax[2][4];
    bool need = false;
#pragma unroll
    for (int qm = 0; qm < 2; ++qm)
#pragma unroll
      for (int r = 0; r < 4; ++r){
        pmax[qm][r] = fmaxf(fmaxf(sa[qm][0][r], sa[qm][1][r]),
                            fmaxf(sa[qm][2][r], sa[qm][3][r]));
        need = need || (pmax[qm][r] > mrun[qm][r] + THRRAW);
      }
    if (__any(need)){
#pragma unroll
      for (int qm = 0; qm < 2; ++qm)
#pragma unroll
        for (int r = 0; r < 4; ++r){
          float mx = pmax[qm][r];
#pragma unroll
          for (int d = 1; d < 16; d <<= 1) mx = fmaxf(mx, __shfl_xor(mx, d, 64));
          float mnew = fmaxf(mrun[qm][r], mx);
          float al = exp2f((mrun[qm][r] - mnew)*C2);
          lrun[qm][r] *= al;
#pragma unroll
          for (int dt = 0; dt < 6; ++dt) Oacc[qm][dt][r] *= al;
          mrun[qm][r] = mnew;
        }
    }

#pragma unroll
    for (int qm = 0; qm < 2; ++qm)
#pragma unroll
      for (int r = 0; r < 4; ++r){
        float mc = mrun[qm][r]*C2;
        float s = 0.f;
#pragma unroll
        for (int ct = 0; ct < 4; ++ct){
          float p = exp2f(fmaf(sa[qm][ct][r], C2, -mc));
          sa[qm][ct][r] = p; s += p;
        }
        lrun[qm][r] += s;
      }

    bf16x8 vf[2][6];
#pragma unroll
    for (int ct = 0; ct < 4; ++ct)
#pragma unroll
      for (int r = 0; r < 4; ++r)
        Plds[w][(lg*4 + r)*72 + ct*16 + l15] = f2bf(sa[0][ct][r]);
    __builtin_amdgcn_s_setprio(1);
#pragma unroll
    for (int ks = 0; ks < 2; ++ks){
      bf16x8 pa = *reinterpret_cast<const bf16x8*>(&Plds[w][l15*72 + ks*32 + lg*8]);
#pragma unroll
      for (int dt = 0; dt < 6; ++dt){
        vf[ks][dt] = *reinterpret_cast<const bf16x8*>(&Vlds[cur][((ks*4+lg)*96 + dt*16 + l15)*8]);
        Oacc[0][dt] = __builtin_amdgcn_mfma_f32_16x16x32_bf16(pa, vf[ks][dt], Oacc[0][dt], 0, 0, 0);
      }
    }
    __builtin_amdgcn_s_setprio(0);
#pragma unroll
    for (int ct = 0; ct < 4; ++ct)
#pragma unroll
      for (int r = 0; r < 4; ++r)
        Plds[w][(lg*4 + r)*72 + ct*16 + l15] = f2bf(sa[1][ct][r]);
    __builtin_amdgcn_s_setprio(1);
#pragma unroll
    for (int ks = 0; ks < 2; ++ks){
      bf16x8 pa = *reinterpret_cast<const bf16x8*>(&Plds[w][l15*72 + ks*32 + lg*8]);
#pragma unroll
      for (int dt = 0; dt < 6; ++dt)
        Oacc[1][dt] = __builtin_amdgcn_mfma_f32_16x16x32_bf16(pa, vf[ks][dt], Oacc[1][dt], 0, 0, 0);
    }
    __builtin_amdgcn_s_setprio(0);

    __syncthreads();
    cur ^= 1;
  }

  // epilogue: reduce l once; fold gate so o = gate * softmax(QK)V
#pragma unroll
  for (int qm = 0; qm < 2; ++qm)
#pragma unroll
    for (int r = 0; r < 4; ++r){
      float l = lrun[qm][r];
#pragma unroll
      for (int d = 1; d < 16; d <<= 1) l += __shfl_xor(l, d, 64);
      int token = tok0 + qm*16 + lg*4 + r;
      float inv = gates[token*HEADS + h] / l;
#pragma unroll
      for (int dt = 0; dt < 6; ++dt)
        o[(size_t)token*DIM + h*HD + dt*16 + l15] = f2bf(Oacc[qm][dt][r]*inv);
    }
}

// ---------------- launch ----------------
extern "C" void kernel_launch(void* const* d_in, const int* in_sizes, int n_in,
                              void* d_out, int out_size, void* d_ws, size_t ws_size,
                              hipStream_t stream) {
  (void)in_sizes; (void)n_in; (void)out_size; (void)ws_size;
  const float* x    = (const float*)d_in[0];
  const float* Wg   = (const float*)d_in[1];
  const float* W1   = (const float*)d_in[2];
  const float* W2   = (const float*)d_in[3];
  const float* Wkv  = (const float*)d_in[4];
  const float* bkv  = (const float*)d_in[5];
  const int*   task = (const int*)d_in[6];

  char* ws = (char*)d_ws;
  short* xb    = (short*)(ws + OFF_XB);
  short* o     = (short*)(ws + OFF_XB);    // alias: xb dead after GEMM1
  short* Bt1   = (short*)(ws + OFF_BT1);
  short* W2t   = (short*)(ws + OFF_W2T);
  short* Kp    = (short*)(ws + OFF_K);
  short* Vp    = (short*)(ws + OFF_VT);
  float* gates = (float*)(ws + OFF_GATE);
  int*   topi  = (int*)(ws + OFF_TOPI);
  float* aux   = (float*)(ws + OFF_AUX);
  short* allq  = (short*)(ws + OFF_ALLQ);
  float* part  = (float*)(ws + OFF_PART);  // alias: dead before gemm1 writes allq
  float* out   = (float*)d_out;

  hipMemsetAsync(aux, 0, 256, stream);
  prep_kernel   <<<14592, 256, 0, stream>>>(W1, Wkv, W2, Bt1, W2t);
  // gating: G1 partials (also emits bf16 x), G2 combine+select+aux
  gating_partial<<<1024, 64, 0, stream>>>(x, Wg, task, xb, part);
  gating_select <<<128, 64, 0, stream>>>(part, topi, gates, aux);
  aux_final     <<<1, 64, 0, stream>>>(aux, out + (size_t)TOK*DIM);
  // all_q (+ kv columns): [8192,768] x [768,2560]
  gemm_bt<true><<<dim3(NQP/128, TOK/128), 256, 0, stream>>>(xb, Bt1, allq, TOK, NQP, DIM);
  split_kv_tile<<<128, 256, 0, stream>>>(allq, bkv, Kp, Vp);
  attn_fwd     <<<dim3(8, 64), 256, 0, stream>>>(allq, topi, gates, Kp, Vp, o);
  // out = mixed(gated o) @ W2 : [8192,2304] x [2304,768], A built in-kernel
  gemm2_fused  <<<dim3(DIM/64, TOK/128), 256, 0, stream>>>(o, topi, W2t, out);
}

// Round 11
// 203.890 us; speedup vs baseline: 1.2951x; 1.2951x over previous
//
#include <hip/hip_runtime.h>
#include <hip/hip_bf16.h>
#include <stdint.h>

#define DEVFN static __device__ __forceinline__

typedef __attribute__((ext_vector_type(8))) short bf16x8;
typedef __attribute__((ext_vector_type(4))) short s16x4;
typedef __attribute__((ext_vector_type(4))) float f32x4;

static constexpr int TOK = 8192;       // B*N
static constexpr int DIM = 768;
static constexpr int HEADS = 8;
static constexpr int HD = 96;
static constexpr int EXPERTS = 24;
static constexpr int NQ = 2304;        // EXPERTS*HD
static constexpr int NQP = 2560;       // NQ + 192 (kv) + 64 (zero pad)
static constexpr float C2 = 0.14724484f;   // HD^-0.5 * log2(e)
static constexpr float THRRAW = 78.0f;     // defer-max threshold, raw-score units

// ---- workspace layout (bytes) ----
static constexpr size_t OFF_XB   = 0;          // x bf16 [8192][768]   (o aliases)
static constexpr size_t OFF_BT1  = 12582912;   // Bt1 bf16 [2560][768]
static constexpr size_t OFF_W2T  = 16515072;   // W2t bf16 [768][2304]
static constexpr size_t OFF_K    = 20054016;   // Kp packed bf16 [128 tiles][12][64][8]
static constexpr size_t OFF_VT   = 21626880;   // Vp packed bf16 [128 tiles][8][96][8]
static constexpr size_t OFF_GATE = 23199744;   // gates f32 [8192][8]
static constexpr size_t OFF_TOPI = 23461888;   // topi i32 [8192][8]
static constexpr size_t OFF_AUX  = 23724032;   // me[24], fe[24], z
static constexpr size_t OFF_ALLQ = 23724288;   // allq bf16 [8192][2560]
// gating partials [8][24][8192] f32 = 6.29 MB + logitsT [24][8192] f32 = 0.79 MB,
// both alias into ALLQ region (dead before gemm1 writes allq)
static constexpr size_t OFF_PART = OFF_ALLQ;
static constexpr size_t OFF_LOGT = OFF_ALLQ + 6291456;

DEVFN short f2bf(float f){
  __hip_bfloat16 h = __float2bfloat16(f);
  return __builtin_bit_cast(short, h);
}
DEVFN float bf2f(short u){
  return __bfloat162float(__builtin_bit_cast(__hip_bfloat16, u));
}

DEVFN void gload16(const void* g, void* l){
  auto gp = reinterpret_cast<__attribute__((address_space(1))) unsigned int*>(
      reinterpret_cast<uintptr_t>(g));
  auto lp = reinterpret_cast<__attribute__((address_space(3))) unsigned int*>(
      reinterpret_cast<uintptr_t>(l));
  __builtin_amdgcn_global_load_lds(gp, lp, 16, 0, 0);
}

// ---------------- fused prep: weight casts / transposes ----------------
__global__ __launch_bounds__(256) void prep_kernel(const float* __restrict__ W1,
                                                   const float* __restrict__ Wkv,
                                                   const float* __restrict__ W2,
                                                   short* __restrict__ Bt1,
                                                   short* __restrict__ W2t){
  int bid = blockIdx.x, tid = threadIdx.x;
  if (bid < 6912){                                    // W1 -> Bt1[n][k]
    int i = bid*256 + tid;                            // 24*768*96
    int e = i / (DIM*HD);
    int rem = i - e*(DIM*HD);
    int d = rem / HD, hh = rem - d*HD;
    Bt1[(size_t)(e*HD + hh)*DIM + d] = f2bf(W1[i]);
  } else if (bid < 7488){                             // Wkv -> Bt1 kv rows
    int i = (bid-6912)*256 + tid;                     // 768*192
    int d = i / 192, j = i - d*192;
    Bt1[(size_t)(NQ + j)*DIM + d] = f2bf(Wkv[i]);
  } else if (bid < 7680){                             // zero pad rows
    int i = (bid-7488)*256 + tid;                     // 64*768
    Bt1[(size_t)(NQ + 192)*DIM + i] = 0;
  } else {                                            // W2 -> W2t[c][e*96+h]
    int i = (bid-7680)*256 + tid;                     // 24*96*768
    int e = i / (HD*DIM);
    int rem = i - e*(HD*DIM);
    int hh = rem / DIM, c = rem - hh*DIM;
    W2t[(size_t)c*NQ + e*HD + hh] = f2bf(W2[i]);
  }
}

// ---------------- gating G1: logit partials, lane=token, W via scalar pipe ----------------
__global__ __launch_bounds__(64) void gating_partial(const float* __restrict__ x,
                                                     const float* __restrict__ Wg,
                                                     const int* __restrict__ task,
                                                     short* __restrict__ xb,
                                                     float* __restrict__ partial){
  __shared__ float xl[64*101];
  int lane = threadIdx.x;
  int tg = blockIdx.x >> 3, kc = blockIdx.x & 7;
  int tok0 = tg*64, kbase = kc*96;
  const float* Wt = Wg + (size_t)task[0]*(DIM*EXPERTS) + (size_t)kbase*EXPERTS;

  // stage x[64][96] (f32, coalesced float4) + write bf16 cast
#pragma unroll
  for (int i = 0; i < 24; ++i){
    int c = i*64 + lane;               // 1536 chunks of 4 floats
    int t = c / 24, cc = c - t*24;
    size_t gidx = (size_t)(tok0+t)*DIM + kbase + cc*4;
    float4 v = *reinterpret_cast<const float4*>(x + gidx);
    float* dst = &xl[t*101 + cc*4];
    dst[0] = v.x; dst[1] = v.y; dst[2] = v.z; dst[3] = v.w;
    s16x4 o4;
    o4[0] = f2bf(v.x); o4[1] = f2bf(v.y); o4[2] = f2bf(v.z); o4[3] = f2bf(v.w);
    *reinterpret_cast<s16x4*>(xb + gidx) = o4;
  }
  __syncthreads();

  float acc[EXPERTS];
#pragma unroll
  for (int e = 0; e < EXPERTS; ++e) acc[e] = 0.f;
  for (int d = 0; d < 96; ++d){
    float xv = xl[lane*101 + d];
    const float* wr = Wt + d*EXPERTS;  // wave-uniform address -> scalar loads
#pragma unroll
    for (int e = 0; e < EXPERTS; ++e) acc[e] = fmaf(xv, wr[e], acc[e]);
  }
#pragma unroll
  for (int e = 0; e < EXPERTS; ++e)
    partial[(size_t)(kc*EXPERTS + e)*TOK + tok0 + lane] = acc[e];
}

// ---------------- gating G2a: combine partials over kc (coalesced, deterministic order) ----------------
__global__ __launch_bounds__(256) void gating_combine(const float* __restrict__ partial,
                                                      float* __restrict__ logT){
  int idx = blockIdx.x*256 + threadIdx.x;      // [e][token] linear, 24*8192
  float s = 0.f;
#pragma unroll
  for (int kc = 0; kc < 8; ++kc)
    s += partial[(size_t)kc*EXPERTS*TOK + idx];  // ascending kc: same order as before
  logT[idx] = s;
}

// ---------------- gating G2b: top-8 select + gates + aux (24 coalesced loads/thread) ----------------
__global__ __launch_bounds__(256) void gating_select(const float* __restrict__ logT,
                                                     int* __restrict__ topi,
                                                     float* __restrict__ gates,
                                                     float* __restrict__ auxbuf){
  __shared__ float lme[EXPERTS];
  __shared__ float lfr[EXPERTS];
  __shared__ float lz;
  int tid = threadIdx.x;
  int lane = tid & 63;
  int token = blockIdx.x*256 + tid;
  if (tid < EXPERTS){ lme[tid] = 0.f; lfr[tid] = 0.f; }
  if (tid == 0) lz = 0.f;
  __syncthreads();

  float acc[EXPERTS];
#pragma unroll
  for (int e = 0; e < EXPERTS; ++e)
    acc[e] = logT[(size_t)e*TOK + token];      // coalesced, 24 independent loads

  // top-8 (strict >, lowest index wins ties -> matches lax.top_k on f32 logits)
  float mx = acc[0];
#pragma unroll
  for (int e = 1; e < EXPERTS; ++e) mx = fmaxf(mx, acc[e]);
  unsigned selm = 0; int sel[8]; float sg[8];
#pragma unroll
  for (int t = 0; t < 8; ++t){
    float best = -3.0e38f; int bi = 0;
#pragma unroll
    for (int e = 0; e < EXPERTS; ++e){
      bool ok = !((selm>>e)&1u) && (acc[e] > best);
      best = ok ? acc[e] : best;
      bi   = ok ? e      : bi;
    }
    selm |= (1u<<bi); sel[t] = bi; sg[t] = best;
  }

  float p[EXPERTS]; float S = 0.f;
#pragma unroll
  for (int e = 0; e < EXPERTS; ++e){ p[e] = __expf(acc[e] - mx); S += p[e]; }
  float lse = mx + __logf(S);
  float Sinv = 1.f/S;
  float gsum = 0.f; float pg[8];
#pragma unroll
  for (int t = 0; t < 8; ++t){ pg[t] = __expf(sg[t] - mx)*Sinv; gsum += pg[t]; }
  float dinv = 1.f/(gsum + 1e-6f);

#pragma unroll
  for (int t = 0; t < 8; ++t){
    topi[token*HEADS + t]  = sel[t];
    gates[token*HEADS + t] = pg[t]*dinv;
  }

  // aux, per wave: me butterfly-reduce, fe via ballot+popc, z butterfly; LDS-stage
  float z2 = lse*lse;
#pragma unroll
  for (int d = 1; d < 64; d <<= 1) z2 += __shfl_xor(z2, d, 64);
#pragma unroll
  for (int e = 0; e < EXPERTS; ++e){
    float v = p[e]*Sinv;
#pragma unroll
    for (int d = 1; d < 64; d <<= 1) v += __shfl_xor(v, d, 64);
    bool hit = (sel[0]==e)|(sel[1]==e)|(sel[2]==e)|(sel[3]==e)|
               (sel[4]==e)|(sel[5]==e)|(sel[6]==e)|(sel[7]==e);
    unsigned long long bal = __ballot(hit);
    if (lane == 0){
      atomicAdd(&lme[e], v);
      atomicAdd(&lfr[e], (float)__popcll(bal));
    }
  }
  if (lane == 0) atomicAdd(&lz, z2);
  __syncthreads();
  if (tid < EXPERTS){
    atomicAdd(&auxbuf[tid], lme[tid]);
    atomicAdd(&auxbuf[EXPERTS + tid], lfr[tid]);
  } else if (tid == 63) atomicAdd(&auxbuf[2*EXPERTS], lz);
}

__global__ void aux_final(const float* __restrict__ auxbuf, float* __restrict__ outa){
  if (threadIdx.x != 0 || blockIdx.x != 0) return;
  float ms = 0.f, fs = 0.f;
  for (int e=0;e<EXPERTS;++e){ ms += auxbuf[e]; fs += auxbuf[EXPERTS+e]; }
  float sw = 0.f;
  for (int e=0;e<EXPERTS;++e) sw += (auxbuf[e]/ms)*(auxbuf[EXPERTS+e]/fs);
  sw *= (float)EXPERTS;
  float z = auxbuf[2*EXPERTS] / (float)TOK;
  outa[0] = 0.1f*sw + 0.001f*z;
}

// ---------------- bf16 MFMA GEMM: 128x128 tile, XCD swizzle, T2 LDS swizzle ----------------
template<bool OUT_BF16>
__global__ __launch_bounds__(256) void gemm_bt(const short* __restrict__ A,
                                               const short* __restrict__ Bt,
                                               void* __restrict__ Cout,
                                               int M, int N, int K){
  __shared__ short As[128*64];
  __shared__ short Bs[128*64];
  int nwg = gridDim.x*gridDim.y;
  int orig = blockIdx.y*gridDim.x + blockIdx.x;
  int cpx = nwg >> 3;
  int swz = (orig & 7)*cpx + (orig >> 3);   // requires nwg % 8 == 0
  int bx = swz % gridDim.x, by = swz / gridDim.x;

  int tid = threadIdx.x;
  int lane = tid & 63, w = tid >> 6;
  int wr = w >> 1, wc = w & 1;
  int l15 = lane & 15, lg = lane >> 4;
  int m0 = by * 128, n0 = bx * 128;

  f32x4 acc[4][4] = {};

  for (int k0 = 0; k0 < K; k0 += 64){
#pragma unroll
    for (int it = 0; it < 4; ++it){
      int c = it*256 + tid;
      int row = c >> 3, cc = c & 7;
      int csrc = cc ^ (row & 7);            // pre-swizzled source chunk
      gload16(A  + (size_t)(m0+row)*K + k0 + csrc*8, (char*)As + (size_t)c*16);
      gload16(Bt + (size_t)(n0+row)*K + k0 + csrc*8, (char*)Bs + (size_t)c*16);
    }
    __syncthreads();
#pragma unroll
    for (int kk = 0; kk < 2; ++kk){
      bf16x8 af[4], bfr[4];
      int jp = (kk*4 + lg) ^ (l15 & 7);     // phys chunk for logical kk*4+lg
#pragma unroll
      for (int m = 0; m < 4; ++m)
        af[m] = *reinterpret_cast<const bf16x8*>(&As[(wr*64 + m*16 + l15)*64 + jp*8]);
#pragma unroll
      for (int n = 0; n < 4; ++n)
        bfr[n] = *reinterpret_cast<const bf16x8*>(&Bs[(wc*64 + n*16 + l15)*64 + jp*8]);
#pragma unroll
      for (int m = 0; m < 4; ++m)
#pragma unroll
        for (int n = 0; n < 4; ++n)
          acc[m][n] = __builtin_amdgcn_mfma_f32_16x16x32_bf16(af[m], bfr[n], acc[m][n], 0, 0, 0);
    }
    __syncthreads();
  }
#pragma unroll
  for (int m = 0; m < 4; ++m)
#pragma unroll
    for (int n = 0; n < 4; ++n){
      int rbase = m0 + wr*64 + m*16 + lg*4;
      int col   = n0 + wc*64 + n*16 + l15;
#pragma unroll
      for (int r = 0; r < 4; ++r){
        float v = acc[m][n][r];
        size_t idx = (size_t)(rbase + r)*N + col;
        if constexpr (OUT_BF16) ((short*)Cout)[idx] = f2bf(v);
        else                    ((float*)Cout)[idx] = v;
      }
    }
}

// ---------------- GEMM2 fused: dbuf LDS + T14 async gather pipeline ----------------
__global__ __launch_bounds__(256) void gemm2_fused(const short* __restrict__ o,
                                                   const int* __restrict__ topi,
                                                   const short* __restrict__ W2t,
                                                   float* __restrict__ out){
  __shared__ short As[2][128*64];
  __shared__ short Bs[2][64*64];
  __shared__ signed char hmap[128][24];
  int nwg = gridDim.x*gridDim.y;
  int orig = blockIdx.y*gridDim.x + blockIdx.x;
  int cpx = nwg >> 3;
  int swz = (orig & 7)*cpx + (orig >> 3);   // 12*64=768, %8==0
  int bx = swz % gridDim.x, by = swz / gridDim.x;

  int tid = threadIdx.x;
  int lane = tid & 63, w = tid >> 6;
  int l15 = lane & 15, lg = lane >> 4;
  int m0 = by * 128, n0 = bx * 64;

  int* hm32 = (int*)&hmap[0][0];
  for (int i = tid; i < 768; i += 256) hm32[i] = -1;   // all bytes 0xFF
  __syncthreads();
  for (int i = tid; i < 128*8; i += 256){
    int row = i >> 3, hh = i & 7;
    int e = topi[(size_t)(m0+row)*HEADS + hh];
    hmap[row][e] = (signed char)hh;
  }
  __syncthreads();

  // per-thread A-gather invariants: 4 chunks (row, cc)
  int arow[4], accv[4];
  size_t arbase[4];
#pragma unroll
  for (int it = 0; it < 4; ++it){
    int c = it*256 + tid;
    arow[it] = c >> 3; accv[it] = c & 7;
    arbase[it] = (size_t)(m0 + arow[it])*DIM;
  }

  f32x4 acc[2][4] = {};
  bf16x8 areg[4];

  // ---- staging helpers (inline) ----
#define STAGE_A(kt, dst)                                                     \
  {                                                                          \
    _Pragma("unroll")                                                        \
    for (int it = 0; it < 4; ++it){                                          \
      unsigned kc = (unsigned)((kt)*8 + accv[it]);                           \
      unsigned e = kc / 12u;                                                 \
      unsigned dc = kc - e*12u;                                              \
      int hh = hmap[arow[it]][e];                                            \
      bf16x8 av = {};                                                        \
      if (hh >= 0)                                                           \
        av = *reinterpret_cast<const bf16x8*>(o + arbase[it] + hh*HD + dc*8);\
      dst[it] = av;                                                          \
    }                                                                        \
  }
#define WRITE_A(buf, src)                                                    \
  {                                                                          \
    _Pragma("unroll")                                                        \
    for (int it = 0; it < 4; ++it)                                           \
      *reinterpret_cast<bf16x8*>(                                            \
        &As[buf][arow[it]*64 + ((accv[it] ^ (arow[it] & 7)))*8]) = src[it];  \
  }
#define STAGE_B(kt, buf)                                                     \
  {                                                                          \
    _Pragma("unroll")                                                        \
    for (int it = 0; it < 2; ++it){                                          \
      int c = it*256 + tid;                                                  \
      int row = c >> 3, cc = c & 7;                                          \
      int csrc = cc ^ (row & 7);                                             \
      gload16(W2t + (size_t)(n0+row)*NQ + (kt)*64 + csrc*8,                  \
              (char*)&Bs[buf][0] + (size_t)c*16);                            \
    }                                                                        \
  }

  // prologue
  STAGE_A(0, areg);
  STAGE_B(0, 0);
  WRITE_A(0, areg);
  __syncthreads();

  for (int kt = 0; kt < 36; ++kt){
    int buf = kt & 1;
    bf16x8 anext[4];
    if (kt < 35){
      STAGE_A(kt+1, anext);       // global loads in flight under MFMA
      STAGE_B(kt+1, buf^1);       // gload_lds in flight across barrier
    }
#pragma unroll
    for (int kk = 0; kk < 2; ++kk){
      int jp = (kk*4 + lg) ^ (l15 & 7);
      bf16x8 af[2], bfr[4];
#pragma unroll
      for (int m = 0; m < 2; ++m)
        af[m] = *reinterpret_cast<const bf16x8*>(&As[buf][(w*32 + m*16 + l15)*64 + jp*8]);
#pragma unroll
      for (int n = 0; n < 4; ++n)
        bfr[n] = *reinterpret_cast<const bf16x8*>(&Bs[buf][(n*16 + l15)*64 + jp*8]);
#pragma unroll
      for (int m = 0; m < 2; ++m)
#pragma unroll
        for (int n = 0; n < 4; ++n)
          acc[m][n] = __builtin_amdgcn_mfma_f32_16x16x32_bf16(af[m], bfr[n], acc[m][n], 0, 0, 0);
    }
    if (kt < 35) WRITE_A(buf^1, anext);
    __syncthreads();
  }
#undef STAGE_A
#undef WRITE_A
#undef STAGE_B

#pragma unroll
  for (int m = 0; m < 2; ++m)
#pragma unroll
    for (int n = 0; n < 4; ++n){
      int rbase = m0 + w*32 + m*16 + lg*4;
      int col   = n0 + n*16 + l15;
#pragma unroll
      for (int r = 0; r < 4; ++r)
        out[(size_t)(rbase + r)*DIM + col] = acc[m][n][r];
    }
}

// ---------------- split kv: bias + repack into fragment-chunk order ----------------
__global__ __launch_bounds__(256) void split_kv_tile(const short* __restrict__ allq,
                                                     const float* __restrict__ bkv,
                                                     short* __restrict__ Kp,
                                                     short* __restrict__ Vp){
  __shared__ short kv[64*192];
  int bt = blockIdx.x;                 // b*16 + nt
  int b = bt >> 4;
  int tid = threadIdx.x;
#pragma unroll
  for (int it = 0; it < 6; ++it){
    int c = it*256 + tid;              // 1536 chunks of 16B
    int j = c / 24, cc = c - j*24;
    int token = b*1024 + (bt & 15)*64 + j;
    gload16(allq + (size_t)token*NQP + NQ + cc*8, (char*)kv + (size_t)c*16);
  }
  __syncthreads();
#pragma unroll
  for (int it = 0; it < 3; ++it){
    int c = it*256 + tid;              // 768 K chunks
    int kc = c >> 6, j = c & 63;
    bf16x8 v = *reinterpret_cast<const bf16x8*>(&kv[j*192 + kc*8]);
    bf16x8 o8;
#pragma unroll
    for (int e = 0; e < 8; ++e) o8[e] = f2bf(bf2f(v[e]) + bkv[kc*8 + e]);
    *reinterpret_cast<bf16x8*>(Kp + ((size_t)bt*768 + c)*8) = o8;
  }
#pragma unroll
  for (int it = 0; it < 3; ++it){
    int c = it*256 + tid;              // 768 V chunks
    int kc = c / 96, hd = c - kc*96;
    float bias = bkv[96 + hd];
    bf16x8 o8;
#pragma unroll
    for (int e = 0; e < 8; ++e) o8[e] = f2bf(bf2f(kv[(kc*8 + e)*192 + 96 + hd]) + bias);
    *reinterpret_cast<bf16x8*>(Vp + ((size_t)bt*768 + c)*8) = o8;
  }
}

// ---------------- flash attention: 32 q-rows/wave, dbuf staging, lazy softmax, gate-folded ----------------
__global__ __launch_bounds__(256, 2) void attn_fwd(const short* __restrict__ allq,
                                                   const int* __restrict__ topi,
                                                   const float* __restrict__ gates,
                                                   const short* __restrict__ Kp,
                                                   const short* __restrict__ Vp,
                                                   short* __restrict__ o){
  __shared__ short Klds[2][768*8];
  __shared__ short Vlds[2][768*8];
  __shared__ short Plds[4][16*72];
  int qt = blockIdx.x, bh = blockIdx.y;        // qt in [0,8): 128 q-rows per block
  int b = bh >> 3, h = bh & 7;
  int tid = threadIdx.x;
  int lane = tid & 63, w = tid >> 6;
  int l15 = lane & 15, lg = lane >> 4;

  bf16x8 qf[2][3];
  int tok0 = b*1024 + qt*128 + w*32;
#pragma unroll
  for (int qm = 0; qm < 2; ++qm){
    int token = tok0 + qm*16 + l15;
    int qe = topi[token*HEADS + h];
    const short* qp = allq + (size_t)token*NQP + qe*HD;
#pragma unroll
    for (int t = 0; t < 3; ++t)
      qf[qm][t] = *reinterpret_cast<const bf16x8*>(qp + t*32 + lg*8);
  }

  f32x4 Oacc[2][6] = {};
  float mrun[2][4], lrun[2][4];
#pragma unroll
  for (int qm = 0; qm < 2; ++qm)
#pragma unroll
    for (int r = 0; r < 4; ++r){ mrun[qm][r] = -1.0e30f; lrun[qm][r] = 0.f; }

  const short* kb = Kp + (size_t)b*16*768*8;
  const short* vb = Vp + (size_t)b*16*768*8;

#pragma unroll
  for (int it = 0; it < 3; ++it){
    int c = it*256 + tid;
    gload16(kb + (size_t)c*8, (char*)&Klds[0][0] + (size_t)c*16);
    gload16(vb + (size_t)c*8, (char*)&Vlds[0][0] + (size_t)c*16);
  }
  __syncthreads();

  int cur = 0;
  for (int nt = 0; nt < 16; ++nt){
    if (nt < 15){
      const short* kn = kb + (size_t)(nt+1)*768*8;
      const short* vn = vb + (size_t)(nt+1)*768*8;
#pragma unroll
      for (int it = 0; it < 3; ++it){
        int c = it*256 + tid;
        gload16(kn + (size_t)c*8, (char*)&Klds[cur^1][0] + (size_t)c*16);
        gload16(vn + (size_t)c*8, (char*)&Vlds[cur^1][0] + (size_t)c*16);
      }
    }

    f32x4 sa[2][4];
    __builtin_amdgcn_s_setprio(1);
#pragma unroll
    for (int ct = 0; ct < 4; ++ct){
      bf16x8 kf[3];
#pragma unroll
      for (int t = 0; t < 3; ++t)
        kf[t] = *reinterpret_cast<const bf16x8*>(&Klds[cur][((t*4+lg)*64 + ct*16 + l15)*8]);
#pragma unroll
      for (int qm = 0; qm < 2; ++qm){
        f32x4 a = {};
#pragma unroll
        for (int t = 0; t < 3; ++t)
          a = __builtin_amdgcn_mfma_f32_16x16x32_bf16(qf[qm][t], kf[t], a, 0, 0, 0);
        sa[qm][ct] = a;
      }
    }
    __builtin_amdgcn_s_setprio(0);

    float pmax[2][4];
    bool need = false;
#pragma unroll
    for (int qm = 0; qm < 2; ++qm)
#pragma unroll
      for (int r = 0; r < 4; ++r){
        pmax[qm][r] = fmaxf(fmaxf(sa[qm][0][r], sa[qm][1][r]),
                            fmaxf(sa[qm][2][r], sa[qm][3][r]));
        need = need || (pmax[qm][r] > mrun[qm][r] + THRRAW);
      }
    if (__any(need)){
#pragma unroll
      for (int qm = 0; qm < 2; ++qm)
#pragma unroll
        for (int r = 0; r < 4; ++r){
          float mx = pmax[qm][r];
#pragma unroll
          for (int d = 1; d < 16; d <<= 1) mx = fmaxf(mx, __shfl_xor(mx, d, 64));
          float mnew = fmaxf(mrun[qm][r], mx);
          float al = exp2f((mrun[qm][r] - mnew)*C2);
          lrun[qm][r] *= al;
#pragma unroll
          for (int dt = 0; dt < 6; ++dt) Oacc[qm][dt][r] *= al;
          mrun[qm][r] = mnew;
        }
    }

#pragma unroll
    for (int qm = 0; qm < 2; ++qm)
#pragma unroll
      for (int r = 0; r < 4; ++r){
        float mc = mrun[qm][r]*C2;
        float s = 0.f;
#pragma unroll
        for (int ct = 0; ct < 4; ++ct){
          float p = exp2f(fmaf(sa[qm][ct][r], C2, -mc));
          sa[qm][ct][r] = p; s += p;
        }
        lrun[qm][r] += s;
      }

    bf16x8 vf[2][6];
#pragma unroll
    for (int ct = 0; ct < 4; ++ct)
#pragma unroll
      for (int r = 0; r < 4; ++r)
        Plds[w][(lg*4 + r)*72 + ct*16 + l15] = f2bf(sa[0][ct][r]);
    __builtin_amdgcn_s_setprio(1);
#pragma unroll
    for (int ks = 0; ks < 2; ++ks){
      bf16x8 pa = *reinterpret_cast<const bf16x8*>(&Plds[w][l15*72 + ks*32 + lg*8]);
#pragma unroll
      for (int dt = 0; dt < 6; ++dt){
        vf[ks][dt] = *reinterpret_cast<const bf16x8*>(&Vlds[cur][((ks*4+lg)*96 + dt*16 + l15)*8]);
        Oacc[0][dt] = __builtin_amdgcn_mfma_f32_16x16x32_bf16(pa, vf[ks][dt], Oacc[0][dt], 0, 0, 0);
      }
    }
    __builtin_amdgcn_s_setprio(0);
#pragma unroll
    for (int ct = 0; ct < 4; ++ct)
#pragma unroll
      for (int r = 0; r < 4; ++r)
        Plds[w][(lg*4 + r)*72 + ct*16 + l15] = f2bf(sa[1][ct][r]);
    __builtin_amdgcn_s_setprio(1);
#pragma unroll
    for (int ks = 0; ks < 2; ++ks){
      bf16x8 pa = *reinterpret_cast<const bf16x8*>(&Plds[w][l15*72 + ks*32 + lg*8]);
#pragma unroll
      for (int dt = 0; dt < 6; ++dt)
        Oacc[1][dt] = __builtin_amdgcn_mfma_f32_16x16x32_bf16(pa, vf[ks][dt], Oacc[1][dt], 0, 0, 0);
    }
    __builtin_amdgcn_s_setprio(0);

    __syncthreads();
    cur ^= 1;
  }

  // epilogue: reduce l once; fold gate so o = gate * softmax(QK)V
#pragma unroll
  for (int qm = 0; qm < 2; ++qm)
#pragma unroll
    for (int r = 0; r < 4; ++r){
      float l = lrun[qm][r];
#pragma unroll
      for (int d = 1; d < 16; d <<= 1) l += __shfl_xor(l, d, 64);
      int token = tok0 + qm*16 + lg*4 + r;
      float inv = gates[token*HEADS + h] / l;
#pragma unroll
      for (int dt = 0; dt < 6; ++dt)
        o[(size_t)token*DIM + h*HD + dt*16 + l15] = f2bf(Oacc[qm][dt][r]*inv);
    }
}

// ---------------- launch ----------------
extern "C" void kernel_launch(void* const* d_in, const int* in_sizes, int n_in,
                              void* d_out, int out_size, void* d_ws, size_t ws_size,
                              hipStream_t stream) {
  (void)in_sizes; (void)n_in; (void)out_size; (void)ws_size;
  const float* x    = (const float*)d_in[0];
  const float* Wg   = (const float*)d_in[1];
  const float* W1   = (const float*)d_in[2];
  const float* W2   = (const float*)d_in[3];
  const float* Wkv  = (const float*)d_in[4];
  const float* bkv  = (const float*)d_in[5];
  const int*   task = (const int*)d_in[6];

  char* ws = (char*)d_ws;
  short* xb    = (short*)(ws + OFF_XB);
  short* o     = (short*)(ws + OFF_XB);    // alias: xb dead after GEMM1
  short* Bt1   = (short*)(ws + OFF_BT1);
  short* W2t   = (short*)(ws + OFF_W2T);
  short* Kp    = (short*)(ws + OFF_K);
  short* Vp    = (short*)(ws + OFF_VT);
  float* gates = (float*)(ws + OFF_GATE);
  int*   topi  = (int*)(ws + OFF_TOPI);
  float* aux   = (float*)(ws + OFF_AUX);
  short* allq  = (short*)(ws + OFF_ALLQ);
  float* part  = (float*)(ws + OFF_PART);  // alias: dead before gemm1 writes allq
  float* logT  = (float*)(ws + OFF_LOGT);  // alias: dead before gemm1 writes allq
  float* out   = (float*)d_out;

  hipMemsetAsync(aux, 0, 256, stream);
  prep_kernel   <<<14592, 256, 0, stream>>>(W1, Wkv, W2, Bt1, W2t);
  // gating: G1 partials (also emits bf16 x), G2a combine, G2b select+aux
  gating_partial<<<1024, 64, 0, stream>>>(x, Wg, task, xb, part);
  gating_combine<<<768, 256, 0, stream>>>(part, logT);
  gating_select <<<32, 256, 0, stream>>>(logT, topi, gates, aux);
  aux_final     <<<1, 64, 0, stream>>>(aux, out + (size_t)TOK*DIM);
  // all_q (+ kv columns): [8192,768] x [768,2560]
  gemm_bt<true><<<dim3(NQP/128, TOK/128), 256, 0, stream>>>(xb, Bt1, allq, TOK, NQP, DIM);
  split_kv_tile<<<128, 256, 0, stream>>>(allq, bkv, Kp, Vp);
  attn_fwd     <<<dim3(8, 64), 256, 0, stream>>>(allq, topi, gates, Kp, Vp, o);
  // out = mixed(gated o) @ W2 : [8192,2304] x [2304,768], A built in-kernel
  gemm2_fused  <<<dim3(DIM/64, TOK/128), 256, 0, stream>>>(o, topi, W2t, out);
}

// Round 12
// 187.595 us; speedup vs baseline: 1.4076x; 1.0869x over previous
//
#include <hip/hip_runtime.h>
#include <hip/hip_bf16.h>
#include <stdint.h>

#define DEVFN static __device__ __forceinline__

typedef __attribute__((ext_vector_type(8))) short bf16x8;
typedef __attribute__((ext_vector_type(4))) short s16x4;
typedef __attribute__((ext_vector_type(4))) float f32x4;

static constexpr int TOK = 8192;       // B*N
static constexpr int DIM = 768;
static constexpr int HEADS = 8;
static constexpr int HD = 96;
static constexpr int EXPERTS = 24;
static constexpr int NQ = 2304;        // EXPERTS*HD
static constexpr int NQP = 2560;       // NQ + 192 (kv) + 64 (zero pad)
static constexpr float C2 = 0.14724484f;   // HD^-0.5 * log2(e)
static constexpr float THRRAW = 78.0f;     // defer-max threshold, raw-score units

// ---- workspace layout (bytes) ----
static constexpr size_t OFF_XB   = 0;          // x bf16 [8192][768]   (o aliases)
static constexpr size_t OFF_BT1  = 12582912;   // Bt1 bf16 [2560][768]
static constexpr size_t OFF_W2T  = 16515072;   // W2t bf16 [768][2304]
static constexpr size_t OFF_K    = 20054016;   // Kp packed bf16 [128 tiles][12][64][8]
static constexpr size_t OFF_VT   = 21626880;   // Vp packed bf16 [128 tiles][8][96][8]
static constexpr size_t OFF_GATE = 23199744;   // gates f32 [8192][8]
static constexpr size_t OFF_TOPI = 23461888;   // topi i32 [8192][8]
static constexpr size_t OFF_AUX  = 23724032;   // me[24], fe[24], z
static constexpr size_t OFF_ALLQ = 23724288;   // allq bf16 [8192][2560]
// gating partials [16][24][8192] f32 = 12.58 MB + logitsT [24][8192] f32 = 0.79 MB,
// both alias into ALLQ region (dead before gemm1 writes allq)
static constexpr size_t OFF_PART = OFF_ALLQ;
static constexpr size_t OFF_LOGT = OFF_ALLQ + 12582912;

DEVFN short f2bf(float f){
  __hip_bfloat16 h = __float2bfloat16(f);
  return __builtin_bit_cast(short, h);
}
DEVFN float bf2f(short u){
  return __bfloat162float(__builtin_bit_cast(__hip_bfloat16, u));
}

DEVFN void gload16(const void* g, void* l){
  auto gp = reinterpret_cast<__attribute__((address_space(1))) unsigned int*>(
      reinterpret_cast<uintptr_t>(g));
  auto lp = reinterpret_cast<__attribute__((address_space(3))) unsigned int*>(
      reinterpret_cast<uintptr_t>(l));
  __builtin_amdgcn_global_load_lds(gp, lp, 16, 0, 0);
}

// ---------------- prep v2: LDS tile transposes, coalesced both sides ----------------
// bid ranges: [0,288) W1 -> Bt1 ; [288,312) Wkv -> Bt1 kv rows ; [312,600) W2 -> W2t ;
// [600,792) zero pad rows.
__global__ __launch_bounds__(256) void prep_kernel(const float* __restrict__ W1,
                                                   const float* __restrict__ Wkv,
                                                   const float* __restrict__ W2,
                                                   short* __restrict__ Bt1,
                                                   short* __restrict__ W2t){
  __shared__ float tl[6240];
  int bid = blockIdx.x, tid = threadIdx.x;

  if (bid < 288){
    // W1[e][768][96] -> Bt1[e*96+hh][768]; tile: 64 d x 96 hh
    int e = bid / 12, dt = bid - e*12;
    int d0 = dt*64;
    const float* src = W1 + (size_t)e*(DIM*HD);
#pragma unroll
    for (int it = 0; it < 6; ++it){
      int c = it*256 + tid;              // 1536 float4 chunks: row=d (64), q (24)
      int row = c / 24, q = c - row*24;
      float4 v = *reinterpret_cast<const float4*>(src + (size_t)(d0+row)*HD + q*4);
      float* dst = &tl[row*97 + q*4];
      dst[0]=v.x; dst[1]=v.y; dst[2]=v.z; dst[3]=v.w;
    }
    __syncthreads();
#pragma unroll
    for (int it = 0; it < 6; ++it){
      int c = it*256 + tid;              // 1536 short4 chunks: hh (96) x cq (16)
      int hh = c >> 4, cq = c & 15;
      s16x4 o4;
#pragma unroll
      for (int j = 0; j < 4; ++j) o4[j] = f2bf(tl[(cq*4+j)*97 + hh]);
      *reinterpret_cast<s16x4*>(Bt1 + (size_t)(e*HD + hh)*DIM + d0 + cq*4) = o4;
    }
  } else if (bid < 312){
    // Wkv[768][192] -> Bt1[NQ+j][768]; tile: 64 d x 96 j
    int t = bid - 288;
    int jb = t / 12, dt = t - jb*12;
    int j0 = jb*96, d0 = dt*64;
#pragma unroll
    for (int it = 0; it < 6; ++it){
      int c = it*256 + tid;
      int row = c / 24, q = c - row*24;
      float4 v = *reinterpret_cast<const float4*>(Wkv + (size_t)(d0+row)*192 + j0 + q*4);
      float* dst = &tl[row*97 + q*4];
      dst[0]=v.x; dst[1]=v.y; dst[2]=v.z; dst[3]=v.w;
    }
    __syncthreads();
#pragma unroll
    for (int it = 0; it < 6; ++it){
      int c = it*256 + tid;
      int jj = c >> 4, cq = c & 15;
      s16x4 o4;
#pragma unroll
      for (int j = 0; j < 4; ++j) o4[j] = f2bf(tl[(cq*4+j)*97 + jj]);
      *reinterpret_cast<s16x4*>(Bt1 + (size_t)(NQ + j0 + jj)*DIM + d0 + cq*4) = o4;
    }
  } else if (bid < 600){
    // W2[e][96][768] -> W2t[c][e*96+hh]; tile: 96 hh x 64 c
    int t = bid - 312;
    int e = t / 12, ct = t - e*12;
    int c0 = ct*64;
    const float* src = W2 + (size_t)e*(HD*DIM);
#pragma unroll
    for (int it = 0; it < 6; ++it){
      int c = it*256 + tid;              // 1536 float4: hh (96) x q (16)
      int hh = c >> 4, q = c & 15;
      float4 v = *reinterpret_cast<const float4*>(src + (size_t)hh*DIM + c0 + q*4);
      float* dst = &tl[hh*65 + q*4];
      dst[0]=v.x; dst[1]=v.y; dst[2]=v.z; dst[3]=v.w;
    }
    __syncthreads();
#pragma unroll
    for (int it = 0; it < 6; ++it){
      int c = it*256 + tid;              // 1536 short4: cr (64) x q (24)
      int cr = c / 24, q = c - cr*24;
      s16x4 o4;
#pragma unroll
      for (int j = 0; j < 4; ++j) o4[j] = f2bf(tl[(q*4+j)*65 + cr]);
      *reinterpret_cast<s16x4*>(W2t + (size_t)(c0 + cr)*NQ + e*HD + q*4) = o4;
    }
  } else {
    // zero pad rows [NQ+192, NQP) of Bt1
    int i = (bid-600)*256 + tid;         // 64*768 = 49152
    Bt1[(size_t)(NQ + 192)*DIM + i] = 0;
  }
}

// ---------------- gating G1: logit partials, lane=token, W via scalar pipe ----------------
// kc split 16 (48 d each) -> 2048 waves (8/CU) to hide the s_load/ds_read chain.
__global__ __launch_bounds__(64) void gating_partial(const float* __restrict__ x,
                                                     const float* __restrict__ Wg,
                                                     const int* __restrict__ task,
                                                     short* __restrict__ xb,
                                                     float* __restrict__ partial){
  __shared__ float xl[64*49];
  int lane = threadIdx.x;
  int tg = blockIdx.x >> 4, kc = blockIdx.x & 15;
  int tok0 = tg*64, kbase = kc*48;
  const float* Wt = Wg + (size_t)task[0]*(DIM*EXPERTS) + (size_t)kbase*EXPERTS;

  // stage x[64 tok][48 d] (f32, coalesced float4) + write bf16 cast
#pragma unroll
  for (int i = 0; i < 12; ++i){
    int c = i*64 + lane;               // 768 chunks of 4 floats
    int t = c / 12, cc = c - t*12;
    size_t gidx = (size_t)(tok0+t)*DIM + kbase + cc*4;
    float4 v = *reinterpret_cast<const float4*>(x + gidx);
    float* dst = &xl[t*49 + cc*4];
    dst[0] = v.x; dst[1] = v.y; dst[2] = v.z; dst[3] = v.w;
    s16x4 o4;
    o4[0] = f2bf(v.x); o4[1] = f2bf(v.y); o4[2] = f2bf(v.z); o4[3] = f2bf(v.w);
    *reinterpret_cast<s16x4*>(xb + gidx) = o4;
  }
  __syncthreads();

  float acc[EXPERTS];
#pragma unroll
  for (int e = 0; e < EXPERTS; ++e) acc[e] = 0.f;
  for (int d = 0; d < 48; ++d){
    float xv = xl[lane*49 + d];
    const float* wr = Wt + d*EXPERTS;  // wave-uniform address -> scalar loads
#pragma unroll
    for (int e = 0; e < EXPERTS; ++e) acc[e] = fmaf(xv, wr[e], acc[e]);
  }
#pragma unroll
  for (int e = 0; e < EXPERTS; ++e)
    partial[(size_t)(kc*EXPERTS + e)*TOK + tok0 + lane] = acc[e];
}

// ---------------- gating G2a: combine partials over kc (coalesced, deterministic order) ----------------
__global__ __launch_bounds__(256) void gating_combine(const float* __restrict__ partial,
                                                      float* __restrict__ logT){
  int idx = blockIdx.x*256 + threadIdx.x;      // [e][token] linear, 24*8192
  float s = 0.f;
#pragma unroll
  for (int kc = 0; kc < 16; ++kc)
    s += partial[(size_t)kc*EXPERTS*TOK + idx];  // ascending kc: deterministic
  logT[idx] = s;
}

// ---------------- gating G2b: top-8 select + gates + aux (24 coalesced loads/thread) ----------------
__global__ __launch_bounds__(256) void gating_select(const float* __restrict__ logT,
                                                     int* __restrict__ topi,
                                                     float* __restrict__ gates,
                                                     float* __restrict__ auxbuf){
  __shared__ float lme[EXPERTS];
  __shared__ float lfr[EXPERTS];
  __shared__ float lz;
  int tid = threadIdx.x;
  int lane = tid & 63;
  int token = blockIdx.x*256 + tid;
  if (tid < EXPERTS){ lme[tid] = 0.f; lfr[tid] = 0.f; }
  if (tid == 0) lz = 0.f;
  __syncthreads();

  float acc[EXPERTS];
#pragma unroll
  for (int e = 0; e < EXPERTS; ++e)
    acc[e] = logT[(size_t)e*TOK + token];      // coalesced, 24 independent loads

  // top-8 (strict >, lowest index wins ties -> matches lax.top_k on f32 logits)
  float mx = acc[0];
#pragma unroll
  for (int e = 1; e < EXPERTS; ++e) mx = fmaxf(mx, acc[e]);
  unsigned selm = 0; int sel[8]; float sg[8];
#pragma unroll
  for (int t = 0; t < 8; ++t){
    float best = -3.0e38f; int bi = 0;
#pragma unroll
    for (int e = 0; e < EXPERTS; ++e){
      bool ok = !((selm>>e)&1u) && (acc[e] > best);
      best = ok ? acc[e] : best;
      bi   = ok ? e      : bi;
    }
    selm |= (1u<<bi); sel[t] = bi; sg[t] = best;
  }

  float p[EXPERTS]; float S = 0.f;
#pragma unroll
  for (int e = 0; e < EXPERTS; ++e){ p[e] = __expf(acc[e] - mx); S += p[e]; }
  float lse = mx + __logf(S);
  float Sinv = 1.f/S;
  float gsum = 0.f; float pg[8];
#pragma unroll
  for (int t = 0; t < 8; ++t){ pg[t] = __expf(sg[t] - mx)*Sinv; gsum += pg[t]; }
  float dinv = 1.f/(gsum + 1e-6f);

#pragma unroll
  for (int t = 0; t < 8; ++t){
    topi[token*HEADS + t]  = sel[t];
    gates[token*HEADS + t] = pg[t]*dinv;
  }

  // aux, per wave: me butterfly-reduce, fe via ballot+popc, z butterfly; LDS-stage
  float z2 = lse*lse;
#pragma unroll
  for (int d = 1; d < 64; d <<= 1) z2 += __shfl_xor(z2, d, 64);
#pragma unroll
  for (int e = 0; e < EXPERTS; ++e){
    float v = p[e]*Sinv;
#pragma unroll
    for (int d = 1; d < 64; d <<= 1) v += __shfl_xor(v, d, 64);
    bool hit = (sel[0]==e)|(sel[1]==e)|(sel[2]==e)|(sel[3]==e)|
               (sel[4]==e)|(sel[5]==e)|(sel[6]==e)|(sel[7]==e);
    unsigned long long bal = __ballot(hit);
    if (lane == 0){
      atomicAdd(&lme[e], v);
      atomicAdd(&lfr[e], (float)__popcll(bal));
    }
  }
  if (lane == 0) atomicAdd(&lz, z2);
  __syncthreads();
  if (tid < EXPERTS){
    atomicAdd(&auxbuf[tid], lme[tid]);
    atomicAdd(&auxbuf[EXPERTS + tid], lfr[tid]);
  } else if (tid == 63) atomicAdd(&auxbuf[2*EXPERTS], lz);
}

__global__ void aux_final(const float* __restrict__ auxbuf, float* __restrict__ outa){
  if (threadIdx.x != 0 || blockIdx.x != 0) return;
  float ms = 0.f, fs = 0.f;
  for (int e=0;e<EXPERTS;++e){ ms += auxbuf[e]; fs += auxbuf[EXPERTS+e]; }
  float sw = 0.f;
  for (int e=0;e<EXPERTS;++e) sw += (auxbuf[e]/ms)*(auxbuf[EXPERTS+e]/fs);
  sw *= (float)EXPERTS;
  float z = auxbuf[2*EXPERTS] / (float)TOK;
  outa[0] = 0.1f*sw + 0.001f*z;
}

// ---------------- bf16 MFMA GEMM: 128x128 tile, XCD swizzle, T2 LDS swizzle ----------------
template<bool OUT_BF16>
__global__ __launch_bounds__(256) void gemm_bt(const short* __restrict__ A,
                                               const short* __restrict__ Bt,
                                               void* __restrict__ Cout,
                                               int M, int N, int K){
  __shared__ short As[128*64];
  __shared__ short Bs[128*64];
  int nwg = gridDim.x*gridDim.y;
  int orig = blockIdx.y*gridDim.x + blockIdx.x;
  int cpx = nwg >> 3;
  int swz = (orig & 7)*cpx + (orig >> 3);   // requires nwg % 8 == 0
  int bx = swz % gridDim.x, by = swz / gridDim.x;

  int tid = threadIdx.x;
  int lane = tid & 63, w = tid >> 6;
  int wr = w >> 1, wc = w & 1;
  int l15 = lane & 15, lg = lane >> 4;
  int m0 = by * 128, n0 = bx * 128;

  f32x4 acc[4][4] = {};

  for (int k0 = 0; k0 < K; k0 += 64){
#pragma unroll
    for (int it = 0; it < 4; ++it){
      int c = it*256 + tid;
      int row = c >> 3, cc = c & 7;
      int csrc = cc ^ (row & 7);            // pre-swizzled source chunk
      gload16(A  + (size_t)(m0+row)*K + k0 + csrc*8, (char*)As + (size_t)c*16);
      gload16(Bt + (size_t)(n0+row)*K + k0 + csrc*8, (char*)Bs + (size_t)c*16);
    }
    __syncthreads();
#pragma unroll
    for (int kk = 0; kk < 2; ++kk){
      bf16x8 af[4], bfr[4];
      int jp = (kk*4 + lg) ^ (l15 & 7);     // phys chunk for logical kk*4+lg
#pragma unroll
      for (int m = 0; m < 4; ++m)
        af[m] = *reinterpret_cast<const bf16x8*>(&As[(wr*64 + m*16 + l15)*64 + jp*8]);
#pragma unroll
      for (int n = 0; n < 4; ++n)
        bfr[n] = *reinterpret_cast<const bf16x8*>(&Bs[(wc*64 + n*16 + l15)*64 + jp*8]);
#pragma unroll
      for (int m = 0; m < 4; ++m)
#pragma unroll
        for (int n = 0; n < 4; ++n)
          acc[m][n] = __builtin_amdgcn_mfma_f32_16x16x32_bf16(af[m], bfr[n], acc[m][n], 0, 0, 0);
    }
    __syncthreads();
  }
#pragma unroll
  for (int m = 0; m < 4; ++m)
#pragma unroll
    for (int n = 0; n < 4; ++n){
      int rbase = m0 + wr*64 + m*16 + lg*4;
      int col   = n0 + wc*64 + n*16 + l15;
#pragma unroll
      for (int r = 0; r < 4; ++r){
        float v = acc[m][n][r];
        size_t idx = (size_t)(rbase + r)*N + col;
        if constexpr (OUT_BF16) ((short*)Cout)[idx] = f2bf(v);
        else                    ((float*)Cout)[idx] = v;
      }
    }
}

// ---------------- GEMM2 fused: dbuf LDS + T14 async gather pipeline ----------------
__global__ __launch_bounds__(256) void gemm2_fused(const short* __restrict__ o,
                                                   const int* __restrict__ topi,
                                                   const short* __restrict__ W2t,
                                                   float* __restrict__ out){
  __shared__ short As[2][128*64];
  __shared__ short Bs[2][64*64];
  __shared__ signed char hmap[128][24];
  int nwg = gridDim.x*gridDim.y;
  int orig = blockIdx.y*gridDim.x + blockIdx.x;
  int cpx = nwg >> 3;
  int swz = (orig & 7)*cpx + (orig >> 3);   // 12*64=768, %8==0
  int bx = swz % gridDim.x, by = swz / gridDim.x;

  int tid = threadIdx.x;
  int lane = tid & 63, w = tid >> 6;
  int l15 = lane & 15, lg = lane >> 4;
  int m0 = by * 128, n0 = bx * 64;

  int* hm32 = (int*)&hmap[0][0];
  for (int i = tid; i < 768; i += 256) hm32[i] = -1;   // all bytes 0xFF
  __syncthreads();
  for (int i = tid; i < 128*8; i += 256){
    int row = i >> 3, hh = i & 7;
    int e = topi[(size_t)(m0+row)*HEADS + hh];
    hmap[row][e] = (signed char)hh;
  }
  __syncthreads();

  // per-thread A-gather invariants: 4 chunks (row, cc)
  int arow[4], accv[4];
  size_t arbase[4];
#pragma unroll
  for (int it = 0; it < 4; ++it){
    int c = it*256 + tid;
    arow[it] = c >> 3; accv[it] = c & 7;
    arbase[it] = (size_t)(m0 + arow[it])*DIM;
  }

  f32x4 acc[2][4] = {};
  bf16x8 areg[4];

  // ---- staging helpers (inline) ----
#define STAGE_A(kt, dst)                                                     \
  {                                                                          \
    _Pragma("unroll")                                                        \
    for (int it = 0; it < 4; ++it){                                          \
      unsigned kc = (unsigned)((kt)*8 + accv[it]);                           \
      unsigned e = kc / 12u;                                                 \
      unsigned dc = kc - e*12u;                                              \
      int hh = hmap[arow[it]][e];                                            \
      bf16x8 av = {};                                                        \
      if (hh >= 0)                                                           \
        av = *reinterpret_cast<const bf16x8*>(o + arbase[it] + hh*HD + dc*8);\
      dst[it] = av;                                                          \
    }                                                                        \
  }
#define WRITE_A(buf, src)                                                    \
  {                                                                          \
    _Pragma("unroll")                                                        \
    for (int it = 0; it < 4; ++it)                                           \
      *reinterpret_cast<bf16x8*>(                                            \
        &As[buf][arow[it]*64 + ((accv[it] ^ (arow[it] & 7)))*8]) = src[it];  \
  }
#define STAGE_B(kt, buf)                                                     \
  {                                                                          \
    _Pragma("unroll")                                                        \
    for (int it = 0; it < 2; ++it){                                          \
      int c = it*256 + tid;                                                  \
      int row = c >> 3, cc = c & 7;                                          \
      int csrc = cc ^ (row & 7);                                             \
      gload16(W2t + (size_t)(n0+row)*NQ + (kt)*64 + csrc*8,                  \
              (char*)&Bs[buf][0] + (size_t)c*16);                            \
    }                                                                        \
  }

  // prologue
  STAGE_A(0, areg);
  STAGE_B(0, 0);
  WRITE_A(0, areg);
  __syncthreads();

  for (int kt = 0; kt < 36; ++kt){
    int buf = kt & 1;
    bf16x8 anext[4];
    if (kt < 35){
      STAGE_A(kt+1, anext);       // global loads in flight under MFMA
      STAGE_B(kt+1, buf^1);       // gload_lds in flight across barrier
    }
#pragma unroll
    for (int kk = 0; kk < 2; ++kk){
      int jp = (kk*4 + lg) ^ (l15 & 7);
      bf16x8 af[2], bfr[4];
#pragma unroll
      for (int m = 0; m < 2; ++m)
        af[m] = *reinterpret_cast<const bf16x8*>(&As[buf][(w*32 + m*16 + l15)*64 + jp*8]);
#pragma unroll
      for (int n = 0; n < 4; ++n)
        bfr[n] = *reinterpret_cast<const bf16x8*>(&Bs[buf][(n*16 + l15)*64 + jp*8]);
#pragma unroll
      for (int m = 0; m < 2; ++m)
#pragma unroll
        for (int n = 0; n < 4; ++n)
          acc[m][n] = __builtin_amdgcn_mfma_f32_16x16x32_bf16(af[m], bfr[n], acc[m][n], 0, 0, 0);
    }
    if (kt < 35) WRITE_A(buf^1, anext);
    __syncthreads();
  }
#undef STAGE_A
#undef WRITE_A
#undef STAGE_B

#pragma unroll
  for (int m = 0; m < 2; ++m)
#pragma unroll
    for (int n = 0; n < 4; ++n){
      int rbase = m0 + w*32 + m*16 + lg*4;
      int col   = n0 + n*16 + l15;
#pragma unroll
      for (int r = 0; r < 4; ++r)
        out[(size_t)(rbase + r)*DIM + col] = acc[m][n][r];
    }
}

// ---------------- split kv: bias + repack into fragment-chunk order ----------------
__global__ __launch_bounds__(256) void split_kv_tile(const short* __restrict__ allq,
                                                     const float* __restrict__ bkv,
                                                     short* __restrict__ Kp,
                                                     short* __restrict__ Vp){
  __shared__ short kv[64*192];
  int bt = blockIdx.x;                 // b*16 + nt
  int b = bt >> 4;
  int tid = threadIdx.x;
#pragma unroll
  for (int it = 0; it < 6; ++it){
    int c = it*256 + tid;              // 1536 chunks of 16B
    int j = c / 24, cc = c - j*24;
    int token = b*1024 + (bt & 15)*64 + j;
    gload16(allq + (size_t)token*NQP + NQ + cc*8, (char*)kv + (size_t)c*16);
  }
  __syncthreads();
#pragma unroll
  for (int it = 0; it < 3; ++it){
    int c = it*256 + tid;              // 768 K chunks
    int kc = c >> 6, j = c & 63;
    bf16x8 v = *reinterpret_cast<const bf16x8*>(&kv[j*192 + kc*8]);
    bf16x8 o8;
#pragma unroll
    for (int e = 0; e < 8; ++e) o8[e] = f2bf(bf2f(v[e]) + bkv[kc*8 + e]);
    *reinterpret_cast<bf16x8*>(Kp + ((size_t)bt*768 + c)*8) = o8;
  }
#pragma unroll
  for (int it = 0; it < 3; ++it){
    int c = it*256 + tid;              // 768 V chunks
    int kc = c / 96, hd = c - kc*96;
    float bias = bkv[96 + hd];
    bf16x8 o8;
#pragma unroll
    for (int e = 0; e < 8; ++e) o8[e] = f2bf(bf2f(kv[(kc*8 + e)*192 + 96 + hd]) + bias);
    *reinterpret_cast<bf16x8*>(Vp + ((size_t)bt*768 + c)*8) = o8;
  }
}

// ---------------- flash attention: 32 q-rows/wave, dbuf staging, lazy softmax, gate-folded ----------------
__global__ __launch_bounds__(256, 2) void attn_fwd(const short* __restrict__ allq,
                                                   const int* __restrict__ topi,
                                                   const float* __restrict__ gates,
                                                   const short* __restrict__ Kp,
                                                   const short* __restrict__ Vp,
                                                   short* __restrict__ o){
  __shared__ short Klds[2][768*8];
  __shared__ short Vlds[2][768*8];
  __shared__ short Plds[4][16*72];
  int qt = blockIdx.x, bh = blockIdx.y;        // qt in [0,8): 128 q-rows per block
  int b = bh >> 3, h = bh & 7;
  int tid = threadIdx.x;
  int lane = tid & 63, w = tid >> 6;
  int l15 = lane & 15, lg = lane >> 4;

  bf16x8 qf[2][3];
  int tok0 = b*1024 + qt*128 + w*32;
#pragma unroll
  for (int qm = 0; qm < 2; ++qm){
    int token = tok0 + qm*16 + l15;
    int qe = topi[token*HEADS + h];
    const short* qp = allq + (size_t)token*NQP + qe*HD;
#pragma unroll
    for (int t = 0; t < 3; ++t)
      qf[qm][t] = *reinterpret_cast<const bf16x8*>(qp + t*32 + lg*8);
  }

  f32x4 Oacc[2][6] = {};
  float mrun[2][4], lrun[2][4];
#pragma unroll
  for (int qm = 0; qm < 2; ++qm)
#pragma unroll
    for (int r = 0; r < 4; ++r){ mrun[qm][r] = -1.0e30f; lrun[qm][r] = 0.f; }

  const short* kb = Kp + (size_t)b*16*768*8;
  const short* vb = Vp + (size_t)b*16*768*8;

#pragma unroll
  for (int it = 0; it < 3; ++it){
    int c = it*256 + tid;
    gload16(kb + (size_t)c*8, (char*)&Klds[0][0] + (size_t)c*16);
    gload16(vb + (size_t)c*8, (char*)&Vlds[0][0] + (size_t)c*16);
  }
  __syncthreads();

  int cur = 0;
  for (int nt = 0; nt < 16; ++nt){
    if (nt < 15){
      const short* kn = kb + (size_t)(nt+1)*768*8;
      const short* vn = vb + (size_t)(nt+1)*768*8;
#pragma unroll
      for (int it = 0; it < 3; ++it){
        int c = it*256 + tid;
        gload16(kn + (size_t)c*8, (char*)&Klds[cur^1][0] + (size_t)c*16);
        gload16(vn + (size_t)c*8, (char*)&Vlds[cur^1][0] + (size_t)c*16);
      }
    }

    f32x4 sa[2][4];
    __builtin_amdgcn_s_setprio(1);
#pragma unroll
    for (int ct = 0; ct < 4; ++ct){
      bf16x8 kf[3];
#pragma unroll
      for (int t = 0; t < 3; ++t)
        kf[t] = *reinterpret_cast<const bf16x8*>(&Klds[cur][((t*4+lg)*64 + ct*16 + l15)*8]);
#pragma unroll
      for (int qm = 0; qm < 2; ++qm){
        f32x4 a = {};
#pragma unroll
        for (int t = 0; t < 3; ++t)
          a = __builtin_amdgcn_mfma_f32_16x16x32_bf16(qf[qm][t], kf[t], a, 0, 0, 0);
        sa[qm][ct] = a;
      }
    }
    __builtin_amdgcn_s_setprio(0);

    float pmax[2][4];
    bool need = false;
#pragma unroll
    for (int qm = 0; qm < 2; ++qm)
#pragma unroll
      for (int r = 0; r < 4; ++r){
        pmax[qm][r] = fmaxf(fmaxf(sa[qm][0][r], sa[qm][1][r]),
                            fmaxf(sa[qm][2][r], sa[qm][3][r]));
        need = need || (pmax[qm][r] > mrun[qm][r] + THRRAW);
      }
    if (__any(need)){
#pragma unroll
      for (int qm = 0; qm < 2; ++qm)
#pragma unroll
        for (int r = 0; r < 4; ++r){
          float mx = pmax[qm][r];
#pragma unroll
          for (int d = 1; d < 16; d <<= 1) mx = fmaxf(mx, __shfl_xor(mx, d, 64));
          float mnew = fmaxf(mrun[qm][r], mx);
          float al = exp2f((mrun[qm][r] - mnew)*C2);
          lrun[qm][r] *= al;
#pragma unroll
          for (int dt = 0; dt < 6; ++dt) Oacc[qm][dt][r] *= al;
          mrun[qm][r] = mnew;
        }
    }

#pragma unroll
    for (int qm = 0; qm < 2; ++qm)
#pragma unroll
      for (int r = 0; r < 4; ++r){
        float mc = mrun[qm][r]*C2;
        float s = 0.f;
#pragma unroll
        for (int ct = 0; ct < 4; ++ct){
          float p = exp2f(fmaf(sa[qm][ct][r], C2, -mc));
          sa[qm][ct][r] = p; s += p;
        }
        lrun[qm][r] += s;
      }

    bf16x8 vf[2][6];
#pragma unroll
    for (int ct = 0; ct < 4; ++ct)
#pragma unroll
      for (int r = 0; r < 4; ++r)
        Plds[w][(lg*4 + r)*72 + ct*16 + l15] = f2bf(sa[0][ct][r]);
    __builtin_amdgcn_s_setprio(1);
#pragma unroll
    for (int ks = 0; ks < 2; ++ks){
      bf16x8 pa = *reinterpret_cast<const bf16x8*>(&Plds[w][l15*72 + ks*32 + lg*8]);
#pragma unroll
      for (int dt = 0; dt < 6; ++dt){
        vf[ks][dt] = *reinterpret_cast<const bf16x8*>(&Vlds[cur][((ks*4+lg)*96 + dt*16 + l15)*8]);
        Oacc[0][dt] = __builtin_amdgcn_mfma_f32_16x16x32_bf16(pa, vf[ks][dt], Oacc[0][dt], 0, 0, 0);
      }
    }
    __builtin_amdgcn_s_setprio(0);
#pragma unroll
    for (int ct = 0; ct < 4; ++ct)
#pragma unroll
      for (int r = 0; r < 4; ++r)
        Plds[w][(lg*4 + r)*72 + ct*16 + l15] = f2bf(sa[1][ct][r]);
    __builtin_amdgcn_s_setprio(1);
#pragma unroll
    for (int ks = 0; ks < 2; ++ks){
      bf16x8 pa = *reinterpret_cast<const bf16x8*>(&Plds[w][l15*72 + ks*32 + lg*8]);
#pragma unroll
      for (int dt = 0; dt < 6; ++dt)
        Oacc[1][dt] = __builtin_amdgcn_mfma_f32_16x16x32_bf16(pa, vf[ks][dt], Oacc[1][dt], 0, 0, 0);
    }
    __builtin_amdgcn_s_setprio(0);

    __syncthreads();
    cur ^= 1;
  }

  // epilogue: reduce l once; fold gate so o = gate * softmax(QK)V
#pragma unroll
  for (int qm = 0; qm < 2; ++qm)
#pragma unroll
    for (int r = 0; r < 4; ++r){
      float l = lrun[qm][r];
#pragma unroll
      for (int d = 1; d < 16; d <<= 1) l += __shfl_xor(l, d, 64);
      int token = tok0 + qm*16 + lg*4 + r;
      float inv = gates[token*HEADS + h] / l;
#pragma unroll
      for (int dt = 0; dt < 6; ++dt)
        o[(size_t)token*DIM + h*HD + dt*16 + l15] = f2bf(Oacc[qm][dt][r]*inv);
    }
}

// ---------------- launch ----------------
extern "C" void kernel_launch(void* const* d_in, const int* in_sizes, int n_in,
                              void* d_out, int out_size, void* d_ws, size_t ws_size,
                              hipStream_t stream) {
  (void)in_sizes; (void)n_in; (void)out_size; (void)ws_size;
  const float* x    = (const float*)d_in[0];
  const float* Wg   = (const float*)d_in[1];
  const float* W1   = (const float*)d_in[2];
  const float* W2   = (const float*)d_in[3];
  const float* Wkv  = (const float*)d_in[4];
  const float* bkv  = (const float*)d_in[5];
  const int*   task = (const int*)d_in[6];

  char* ws = (char*)d_ws;
  short* xb    = (short*)(ws + OFF_XB);
  short* o     = (short*)(ws + OFF_XB);    // alias: xb dead after GEMM1
  short* Bt1   = (short*)(ws + OFF_BT1);
  short* W2t   = (short*)(ws + OFF_W2T);
  short* Kp    = (short*)(ws + OFF_K);
  short* Vp    = (short*)(ws + OFF_VT);
  float* gates = (float*)(ws + OFF_GATE);
  int*   topi  = (int*)(ws + OFF_TOPI);
  float* aux   = (float*)(ws + OFF_AUX);
  short* allq  = (short*)(ws + OFF_ALLQ);
  float* part  = (float*)(ws + OFF_PART);  // alias: dead before gemm1 writes allq
  float* logT  = (float*)(ws + OFF_LOGT);  // alias: dead before gemm1 writes allq
  float* out   = (float*)d_out;

  hipMemsetAsync(aux, 0, 256, stream);
  prep_kernel   <<<792, 256, 0, stream>>>(W1, Wkv, W2, Bt1, W2t);
  // gating: G1 partials (also emits bf16 x), G2a combine, G2b select+aux
  gating_partial<<<2048, 64, 0, stream>>>(x, Wg, task, xb, part);
  gating_combine<<<768, 256, 0, stream>>>(part, logT);
  gating_select <<<32, 256, 0, stream>>>(logT, topi, gates, aux);
  aux_final     <<<1, 64, 0, stream>>>(aux, out + (size_t)TOK*DIM);
  // all_q (+ kv columns): [8192,768] x [768,2560]
  gemm_bt<true><<<dim3(NQP/128, TOK/128), 256, 0, stream>>>(xb, Bt1, allq, TOK, NQP, DIM);
  split_kv_tile<<<128, 256, 0, stream>>>(allq, bkv, Kp, Vp);
  attn_fwd     <<<dim3(8, 64), 256, 0, stream>>>(allq, topi, gates, Kp, Vp, o);
  // out = mixed(gated o) @ W2 : [8192,2304] x [2304,768], A built in-kernel
  gemm2_fused  <<<dim3(DIM/64, TOK/128), 256, 0, stream>>>(o, topi, W2t, out);
}